// Round 4
// baseline (2558.528 us; speedup 1.0000x reference)
//
#include <hip/hip_runtime.h>
#include <cstdint>
#include <cstddef>

#define NNODES 100000
#define NEDGES 1600000
#define DIM 128
#define NREL 8
#define NSEG (NNODES * NREL)                       // 800,000 segments
#define SCAN_BLK 2048
#define NSCAN ((NSEG + SCAN_BLK - 1) / SCAN_BLK)   // 391 scan blocks
#define NKT 36                                     // 1152 / 32 K-steps
#define AR32 132                                   // fp32 LDS row stride (words)
#define A16ROW 1160                                // f16 LDS row stride (ushorts)

typedef float f32x4 __attribute__((ext_vector_type(4)));
typedef short short8 __attribute__((ext_vector_type(8)));
typedef _Float16 half8 __attribute__((ext_vector_type(8)));

__device__ inline float h2f(unsigned short u) {
    return (float)__builtin_bit_cast(_Float16, u);
}
__device__ inline unsigned short f2h(float f) {
    return __builtin_bit_cast(unsigned short, (_Float16)f);
}

// ---------------------------------------------------------------- counts ----
__global__ __launch_bounds__(256) void count_kernel(const int* __restrict__ dst,
                                                    const int* __restrict__ et,
                                                    int* __restrict__ cnt) {
    int e = blockIdx.x * 256 + threadIdx.x;
    if (e < NEDGES) atomicAdd(&cnt[dst[e] * NREL + et[e]], 1);
}

// ------------------------------------------------- scan pass1 (+inv fuse) ---
__global__ __launch_bounds__(256) void scan_pass1(const int* __restrict__ cnt,
                                                  int* __restrict__ bsum,
                                                  float* __restrict__ inv) {
    int base = blockIdx.x * SCAN_BLK + threadIdx.x * 8;
    int s = 0;
#pragma unroll
    for (int j = 0; j < 8; ++j) {
        int i = base + j;
        if (i < NSEG) {
            int c = cnt[i];
            s += c;
            inv[i] = 1.0f / (float)(c > 1 ? c : 1);
        }
    }
    __shared__ int ws[4];
    for (int d = 1; d < 64; d <<= 1) s += __shfl_xor(s, d);
    int lane = threadIdx.x & 63, w = threadIdx.x >> 6;
    if (lane == 0) ws[w] = s;
    __syncthreads();
    if (threadIdx.x == 0) bsum[blockIdx.x] = ws[0] + ws[1] + ws[2] + ws[3];
}

__global__ __launch_bounds__(64) void scan_pass2(int* __restrict__ bsum) {
    int lane = threadIdx.x;
    int vals[7];
    int s = 0;
#pragma unroll
    for (int j = 0; j < 7; ++j) {
        int i = lane * 7 + j;
        vals[j] = (i < NSCAN) ? bsum[i] : 0;
        s += vals[j];
    }
    int incl = s;
    for (int d = 1; d < 64; d <<= 1) {
        int u = __shfl_up(incl, d);
        if (lane >= d) incl += u;
    }
    int base = incl - s;
#pragma unroll
    for (int j = 0; j < 7; ++j) {
        int i = lane * 7 + j;
        if (i < NSCAN) bsum[i] = base;
        base += vals[j];
    }
}

__global__ __launch_bounds__(256) void scan_pass3(const int* __restrict__ cnt,
                                                  const int* __restrict__ bsum,
                                                  int* __restrict__ segend) {
    int tid = threadIdx.x;
    int base = blockIdx.x * SCAN_BLK + tid * 8;
    int v[8];
    int s = 0;
#pragma unroll
    for (int j = 0; j < 8; ++j) {
        int i = base + j;
        v[j] = (i < NSEG) ? cnt[i] : 0;
        s += v[j];
    }
    int lane = tid & 63, w = tid >> 6;
    int incl = s;
    for (int d = 1; d < 64; d <<= 1) {
        int u = __shfl_up(incl, d);
        if (lane >= d) incl += u;
    }
    __shared__ int wtot[4];
    if (lane == 63) wtot[w] = incl;
    __syncthreads();
    int wbase = 0;
#pragma unroll
    for (int k = 0; k < 4; ++k)
        if (k < w) wbase += wtot[k];
    int tbase = bsum[blockIdx.x] + wbase + (incl - s);
#pragma unroll
    for (int j = 0; j < 8; ++j) {
        int i = base + j;
        if (i < NSEG) segend[i] = tbase;   // becomes segment END after bucketing
        tbase += v[j];
    }
}

// --------------------------------------------------------------- bucket ----
// einfo[p] = { src | (slot_local << 20), bits(inv[seg]) }; slot_local = seg % 64
// (valid because fused_layer blocks cover 8 nodes = 64 aligned segments).
__global__ __launch_bounds__(256) void bucket_kernel(const int* __restrict__ src,
                                                     const int* __restrict__ dst,
                                                     const int* __restrict__ et,
                                                     const float* __restrict__ inv,
                                                     int* __restrict__ segend,
                                                     int2* __restrict__ einfo) {
    int e = blockIdx.x * 256 + threadIdx.x;
    if (e >= NEDGES) return;
    int seg = dst[e] * NREL + et[e];
    int p = atomicAdd(&segend[seg], 1);
    einfo[p] = make_int2(src[e] | ((seg & 63) << 20), __float_as_int(inv[seg]));
}

// --------------------------------------------------------------- fp32->f16 --
__global__ __launch_bounds__(256) void cvt_f16(const float* __restrict__ in,
                                               unsigned short* __restrict__ outp,
                                               int nelem4) {
    int i = blockIdx.x * 256 + threadIdx.x;
    if (i >= nelem4) return;
    float4 v = *(const float4*)(in + (size_t)i * 4);
    ushort4 o = make_ushort4(f2h(v.x), f2h(v.y), f2h(v.z), f2h(v.w));
    *(ushort4*)(outp + (size_t)i * 4) = o;
}

// ----------------------------------------------------- pack W into B-frags --
// B-frag (16x16x32 f16): lane holds B[k=(lane>>4)*8+j][n=lane&15].
__global__ __launch_bounds__(64) void pack_w(const float* __restrict__ Wrel,
                                             const float* __restrict__ Wroot,
                                             unsigned short* __restrict__ Wp) {
    const int kt = blockIdx.x >> 3, ht = blockIdx.x & 7;
    const int lane = threadIdx.x;
    const int col = ht * 16 + (lane & 15);
    const int kbase = kt * 32 + (lane >> 4) * 8;
    unsigned short vals[8];
#pragma unroll
    for (int j = 0; j < 8; ++j) {
        int k = kbase + j;
        float f = (k < 1024) ? Wrel[(size_t)k * 128 + col]
                             : Wroot[(size_t)(k - 1024) * 128 + col];
        vals[j] = f2h(f);
    }
    unsigned short* dstp = Wp + ((size_t)blockIdx.x * 64 + lane) * 8;
#pragma unroll
    for (int j = 0; j < 8; ++j) dstp[j] = vals[j];
}

// ---------------------------------------------------------- fused layer ----
// 8 nodes/block, 256 threads.
// Phase 0: zero fp32 accum tile (64 seg rows) + stage root rows (8).
// Phase 1: flat edge loop, 16 lanes/edge, ds_add_f32 scatter (scale pre-folded).
// Phase 1.5: in-place fp32 -> f16 repack (register-staged, double barrier).
// Phase 2: 4 waves x 2 h-tiles, 36 K-steps mfma_f32_16x16x32_f16.
__global__ __launch_bounds__(256, 4) void fused_layer(
    const unsigned short* __restrict__ feat,   // f16 [N][128]
    const int* __restrict__ segend,
    const int2* __restrict__ einfo,
    const unsigned short* __restrict__ Wp,     // packed f16 B-frags
    const float* __restrict__ bias,
    unsigned short* __restrict__ out) {        // f16 [N][128], relu'd
    __shared__ __align__(16) char LB[72 * AR32 * 4];   // 38,016 B
    float* A32 = (float*)LB;
    unsigned short* A16 = (unsigned short*)LB;
    const int tid = threadIdx.x;
    const int blk = blockIdx.x;

    // ---- phase 0 ----
    for (int i = tid; i < 64 * AR32; i += 256) A32[i] = 0.f;
    {
        const int g = tid >> 5, d4 = (tid & 31) * 4;
        ushort4 rv = *(const ushort4*)(feat + ((size_t)blk * 8 + g) * DIM + d4);
        float* rp = &A32[(64 + g) * AR32 + d4];
        rp[0] = h2f(rv.x); rp[1] = h2f(rv.y); rp[2] = h2f(rv.z); rp[3] = h2f(rv.w);
    }
    __syncthreads();

    // ---- phase 1: edge-parallel scaled scatter ----
    {
        const int slice = tid >> 4, l16 = tid & 15;
        const int segbase = blk * 64;
        const int eb0 = (blk == 0) ? 0 : segend[segbase - 1];
        const int eb1 = segend[segbase + 63];
        int e = eb0 + slice;
        int2 info = make_int2(0, 0);
        if (e < eb1) info = einfo[e];
        while (e < eb1) {
            const int en = e + 16;
            int2 infon = info;
            if (en < eb1) infon = einfo[en];        // prefetch next
            const int srcn = info.x & 0xFFFFF;
            const int slot = ((unsigned)info.x) >> 20;
            const float scale = __int_as_float(info.y);
            const short8 v = *(const short8*)(feat + (size_t)srcn * DIM + l16 * 8);
            float* ap = &A32[slot * AR32 + l16 * 8];
#pragma unroll
            for (int j = 0; j < 8; ++j)
                atomicAdd(ap + j, h2f((unsigned short)v[j]) * scale);
            info = infon;
            e = en;
        }
    }
    __syncthreads();

    // ---- phase 1.5: A32 -> A16 in place ----
    {
        float tmp[36];
#pragma unroll
        for (int i = 0; i < 36; ++i) {
            const int id = tid * 36 + i;            // 0..9215
            const int row = id >> 7, d = id & 127;
            tmp[i] = A32[row * AR32 + d];
        }
        __syncthreads();
#pragma unroll
        for (int i = 0; i < 36; ++i) {
            const int id = tid * 36 + i;
            const int row = id >> 7, d = id & 127;
            const int g = (row < 64) ? (row >> 3) : (row - 64);
            const int k = (row < 64) ? ((row & 7) * 128 + d) : (1024 + d);
            A16[g * A16ROW + k] = f2h(tmp[i]);
        }
    }
    __syncthreads();

    // ---- phase 2: MFMA ----
    const int lane = tid & 63;
    const int w = tid >> 6;                 // wave id -> h-tiles 2w, 2w+1
    const int m8 = lane & 7;                // nodes duplicated for m in 8..15
    const int kq = lane >> 4;
    const unsigned short* arow = &A16[m8 * A16ROW + kq * 8];
    f32x4 acc0 = {0.f, 0.f, 0.f, 0.f};
    f32x4 acc1 = {0.f, 0.f, 0.f, 0.f};

#pragma unroll 4
    for (int kt = 0; kt < NKT; ++kt) {
        short8 a = *(const short8*)(arow + kt * 32);
        short8 b0 = *(const short8*)(Wp + ((size_t)(kt * 8 + 2 * w) * 64 + lane) * 8);
        short8 b1 = *(const short8*)(Wp + ((size_t)(kt * 8 + 2 * w + 1) * 64 + lane) * 8);
        acc0 = __builtin_amdgcn_mfma_f32_16x16x32_f16(
            __builtin_bit_cast(half8, a), __builtin_bit_cast(half8, b0), acc0, 0, 0, 0);
        acc1 = __builtin_amdgcn_mfma_f32_16x16x32_f16(
            __builtin_bit_cast(half8, a), __builtin_bit_cast(half8, b1), acc1, 0, 0, 0);
    }

    // ---- epilogue: bias + relu + f16 store (C/D: col=lane&15, row=quad*4+r) ----
    const int col = lane & 15;
    const int rbase = (lane >> 4) * 4;
    const int h0 = 32 * w + col;
    const int h1 = h0 + 16;
    const float bv0 = bias[h0], bv1 = bias[h1];
#pragma unroll
    for (int r = 0; r < 4; ++r) {
        const int row = rbase + r;
        if (row < 8) {
            const size_t nrow = ((size_t)blk * 8 + row) * DIM;
            out[nrow + h0] = f2h(fmaxf(acc0[r] + bv0, 0.f));
            out[nrow + h1] = f2h(fmaxf(acc1[r] + bv1, 0.f));
        }
    }
}

// ------------------------------------------------------------------ head ----
__global__ __launch_bounds__(256) void final_kernel(const unsigned short* __restrict__ h2,
                                                    const float* __restrict__ w,
                                                    const float* __restrict__ b,
                                                    float* __restrict__ out) {
    int gid = blockIdx.x * 256 + threadIdx.x;
    int node = gid >> 6;
    int lane = gid & 63;
    if (node >= NNODES) return;
    const unsigned short* row = h2 + (size_t)node * DIM;
    float v = h2f(row[lane]) * w[lane] + h2f(row[lane + 64]) * w[lane + 64];
#pragma unroll
    for (int off = 32; off; off >>= 1) v += __shfl_xor(v, off);
    if (lane == 0) out[node] = 1.0f / (1.0f + __expf(-(v + b[0])));
}

// ---------------------------------------------------------------- launch ----
extern "C" void kernel_launch(void* const* d_in, const int* in_sizes, int n_in,
                              void* d_out, int out_size, void* d_ws, size_t ws_size,
                              hipStream_t stream) {
    const float* x      = (const float*)d_in[0];
    const int*   ei     = (const int*)d_in[1];
    const int*   et     = (const int*)d_in[2];
    const float* Wrel1  = (const float*)d_in[3];
    const float* Wroot1 = (const float*)d_in[4];
    const float* b1     = (const float*)d_in[5];
    const float* Wrel2  = (const float*)d_in[6];
    const float* Wroot2 = (const float*)d_in[7];
    const float* b2     = (const float*)d_in[8];
    const float* outw   = (const float*)d_in[9];
    const float* outb   = (const float*)d_in[10];
    const int* src = ei;
    const int* dst = ei + NEDGES;

    // workspace layout (~100 MB, 16B-aligned chunks)
    char* ws = (char*)d_ws;
    int*            cnt    = (int*)(ws + 0);                     //  3,200,000
    int*            bsum   = (int*)(ws + 3200000);               //      4,096
    int*            segend = (int*)(ws + 3204096);               //  3,200,000
    int2*           einfo  = (int2*)(ws + 6404096);              // 12,800,016 (+slack)
    unsigned short* xh     = (unsigned short*)(ws + 19204352);   // 25,600,000
    unsigned short* h1     = (unsigned short*)(ws + 44804352);   // 25,600,000
    unsigned short* h2     = (unsigned short*)(ws + 70404352);   // 25,600,000
    unsigned short* Wp1    = (unsigned short*)(ws + 96004352);   //    294,912
    unsigned short* Wp2    = (unsigned short*)(ws + 96299264);   //    294,912
    float*          inv    = (float*)(ws + 96594176);            //  3,200,000
    // end: 99,794,176 B

    hipMemsetAsync(cnt, 0, (size_t)NSEG * 4, stream);
    count_kernel<<<(NEDGES + 255) / 256, 256, 0, stream>>>(dst, et, cnt);
    scan_pass1<<<NSCAN, 256, 0, stream>>>(cnt, bsum, inv);
    scan_pass2<<<1, 64, 0, stream>>>(bsum);
    scan_pass3<<<NSCAN, 256, 0, stream>>>(cnt, bsum, segend);
    bucket_kernel<<<(NEDGES + 255) / 256, 256, 0, stream>>>(src, dst, et, inv, segend, einfo);

    cvt_f16<<<(NNODES * DIM / 4 + 255) / 256, 256, 0, stream>>>(x, xh, NNODES * DIM / 4);
    pack_w<<<NKT * 8, 64, 0, stream>>>(Wrel1, Wroot1, Wp1);
    pack_w<<<NKT * 8, 64, 0, stream>>>(Wrel2, Wroot2, Wp2);

    fused_layer<<<NNODES / 8, 256, 0, stream>>>(xh, segend, einfo, Wp1, b1, h1);
    fused_layer<<<NNODES / 8, 256, 0, stream>>>(h1, segend, einfo, Wp2, b2, h2);

    final_kernel<<<(NNODES * 64 + 255) / 256, 256, 0, stream>>>(h2, outw, outb, (float*)d_out);
}

// Round 6
// 522.121 us; speedup vs baseline: 4.9003x; 4.9003x over previous
//
#include <hip/hip_runtime.h>
#include <cstdint>
#include <cstddef>

#define NNODES 100000
#define NEDGES 1600000
#define DIM 128
#define NREL 8
#define NSEG (NNODES * NREL)                       // 800,000 segments
#define SCAN_BLK 2048
#define NSCAN ((NSEG + SCAN_BLK - 1) / SCAN_BLK)   // 391 scan blocks
#define NKT 36                                     // 1152 / 32 K-steps
#define A16ROW 1160                                // f16 LDS row stride (ushorts)
#define CVT4 (NNODES * DIM / 4)                    // 3,200,000 float4 groups

typedef float f32x4 __attribute__((ext_vector_type(4)));
typedef short short8 __attribute__((ext_vector_type(8)));
typedef _Float16 half8 __attribute__((ext_vector_type(8)));

__device__ inline float h2f(unsigned short u) {
    return (float)__builtin_bit_cast(_Float16, u);
}
__device__ inline unsigned short f2h(float f) {
    return __builtin_bit_cast(unsigned short, (_Float16)f);
}

// ------------------------------------------------- count + cvt (fused) ----
// NOTE: grid must cover max(NEDGES, CVT4) threads; both parts are guarded.
__global__ __launch_bounds__(256) void count_cvt(const int* __restrict__ dst,
                                                 const int* __restrict__ et,
                                                 int* __restrict__ cnt,
                                                 const float* __restrict__ x,
                                                 unsigned short* __restrict__ xh) {
    int gid = blockIdx.x * 256 + threadIdx.x;
    if (gid < NEDGES) atomicAdd(&cnt[dst[gid] * NREL + et[gid]], 1);
    if (gid < CVT4) {
        float4 v = *(const float4*)(x + (size_t)gid * 4);
        ushort4 o = make_ushort4(f2h(v.x), f2h(v.y), f2h(v.z), f2h(v.w));
        *(ushort4*)(xh + (size_t)gid * 4) = o;
    }
}

// ------------------------------------------------- scan pass1 (+inv fuse) ---
__global__ __launch_bounds__(256) void scan_pass1(const int* __restrict__ cnt,
                                                  int* __restrict__ bsum,
                                                  float* __restrict__ inv) {
    int base = blockIdx.x * SCAN_BLK + threadIdx.x * 8;
    int s = 0;
#pragma unroll
    for (int j = 0; j < 8; ++j) {
        int i = base + j;
        if (i < NSEG) {
            int c = cnt[i];
            s += c;
            inv[i] = 1.0f / (float)(c > 1 ? c : 1);
        }
    }
    __shared__ int ws[4];
    for (int d = 1; d < 64; d <<= 1) s += __shfl_xor(s, d);
    int lane = threadIdx.x & 63, w = threadIdx.x >> 6;
    if (lane == 0) ws[w] = s;
    __syncthreads();
    if (threadIdx.x == 0) bsum[blockIdx.x] = ws[0] + ws[1] + ws[2] + ws[3];
}

__global__ __launch_bounds__(64) void scan_pass2(int* __restrict__ bsum) {
    int lane = threadIdx.x;
    int vals[7];
    int s = 0;
#pragma unroll
    for (int j = 0; j < 7; ++j) {
        int i = lane * 7 + j;
        vals[j] = (i < NSCAN) ? bsum[i] : 0;
        s += vals[j];
    }
    int incl = s;
    for (int d = 1; d < 64; d <<= 1) {
        int u = __shfl_up(incl, d);
        if (lane >= d) incl += u;
    }
    int base = incl - s;
#pragma unroll
    for (int j = 0; j < 7; ++j) {
        int i = lane * 7 + j;
        if (i < NSCAN) bsum[i] = base;
        base += vals[j];
    }
}

__global__ __launch_bounds__(256) void scan_pass3(const int* __restrict__ cnt,
                                                  const int* __restrict__ bsum,
                                                  int* __restrict__ segend) {
    int tid = threadIdx.x;
    int base = blockIdx.x * SCAN_BLK + tid * 8;
    int v[8];
    int s = 0;
#pragma unroll
    for (int j = 0; j < 8; ++j) {
        int i = base + j;
        v[j] = (i < NSEG) ? cnt[i] : 0;
        s += v[j];
    }
    int lane = tid & 63, w = tid >> 6;
    int incl = s;
    for (int d = 1; d < 64; d <<= 1) {
        int u = __shfl_up(incl, d);
        if (lane >= d) incl += u;
    }
    __shared__ int wtot[4];
    if (lane == 63) wtot[w] = incl;
    __syncthreads();
    int wbase = 0;
#pragma unroll
    for (int k = 0; k < 4; ++k)
        if (k < w) wbase += wtot[k];
    int tbase = bsum[blockIdx.x] + wbase + (incl - s);
#pragma unroll
    for (int j = 0; j < 8; ++j) {
        int i = base + j;
        if (i < NSEG) segend[i] = tbase;   // becomes segment END after bucketing
        tbase += v[j];
    }
}

// --------------------------------------------------------------- bucket ----
// einfo[p] = { src | (rel << 20), bits(inv[seg]) }   (src < 2^20)
__global__ __launch_bounds__(256) void bucket_kernel(const int* __restrict__ src,
                                                     const int* __restrict__ dst,
                                                     const int* __restrict__ et,
                                                     const float* __restrict__ inv,
                                                     int* __restrict__ segend,
                                                     int2* __restrict__ einfo) {
    int e = blockIdx.x * 256 + threadIdx.x;
    if (e >= NEDGES) return;
    int seg = dst[e] * NREL + et[e];
    int p = atomicAdd(&segend[seg], 1);
    einfo[p] = make_int2(src[e] | ((seg & 7) << 20), __float_as_int(inv[seg]));
}

// ----------------------------------------------------- pack W into B-frags --
// B-frag (16x16x32 f16): lane holds B[k=(lane>>4)*8+j][n=lane&15].
// Both layers in one launch: blockIdx >= 288 -> layer 2.
__global__ __launch_bounds__(64) void pack_w2(const float* __restrict__ Wrel1,
                                              const float* __restrict__ Wroot1,
                                              const float* __restrict__ Wrel2,
                                              const float* __restrict__ Wroot2,
                                              unsigned short* __restrict__ Wp1,
                                              unsigned short* __restrict__ Wp2) {
    int bb = blockIdx.x;
    const float* Wrel = Wrel1;
    const float* Wroot = Wroot1;
    unsigned short* Wp = Wp1;
    if (bb >= NKT * 8) {
        bb -= NKT * 8;
        Wrel = Wrel2; Wroot = Wroot2; Wp = Wp2;
    }
    const int kt = bb >> 3, ht = bb & 7;
    const int lane = threadIdx.x;
    const int col = ht * 16 + (lane & 15);
    const int kbase = kt * 32 + (lane >> 4) * 8;
    unsigned short vals[8];
#pragma unroll
    for (int j = 0; j < 8; ++j) {
        int k = kbase + j;
        float f = (k < 1024) ? Wrel[(size_t)k * 128 + col]
                             : Wroot[(size_t)(k - 1024) * 128 + col];
        vals[j] = f2h(f);
    }
    unsigned short* dstp = Wp + ((size_t)bb * 64 + lane) * 8;
#pragma unroll
    for (int j = 0; j < 8; ++j) dstp[j] = vals[j];
}

// ---------------------------------------------------------- fused layer ----
// 16 nodes/block, 256 threads, 16 lanes/node.
// Phase 0: zero A-tile + stage root rows.
// Phase 1: 8-deep pipelined CSR gather; fp32 reg accum; flush f16 rows on
//          relation change (edges are segment-sorted so <=8 flushes/node).
// Phase 2: 4 waves x 2 h-tiles, 36 K-steps mfma_f32_16x16x32_f16.
__global__ __launch_bounds__(256, 4) void fused_layer(
    const unsigned short* __restrict__ feat,   // f16 [N][128]
    const int* __restrict__ segend,
    const int2* __restrict__ einfo,
    const unsigned short* __restrict__ Wp,     // packed f16 B-frags
    const float* __restrict__ bias,
    unsigned short* __restrict__ out) {        // f16 [N][128], relu'd
    __shared__ __align__(16) unsigned short A16[16 * A16ROW + 8];
    const int tid = threadIdx.x;
    const int blk = blockIdx.x;
    const int g = tid >> 4, l16 = tid & 15;

    // ---- phase 0: zero tile ----
    {
        int4* z = (int4*)A16;
        for (int i = tid; i < (16 * A16ROW) / 8; i += 256)
            z[i] = make_int4(0, 0, 0, 0);
    }
    __syncthreads();
    // root rows (each thread owns a disjoint 16B slice; read again only after
    // the phase-1 barrier)
    *(short8*)(&A16[g * A16ROW + 1024 + l16 * 8]) =
        *(const short8*)(feat + ((size_t)blk * 16 + g) * DIM + l16 * 8);

    // ---- phase 1: pipelined gather ----
    {
        const int n = blk * 16 + g;
        const int segbase = n * NREL;
        const int beg = (segbase == 0) ? 0 : segend[segbase - 1];
        const int end = segend[segbase + 7];
        unsigned short* Arow = &A16[g * A16ROW];

        if (beg < end) {
            const int last = end - 1;
            int2 q[8], qn[8];
            short8 v[8];
#pragma unroll
            for (int u = 0; u < 8; ++u) {
                int p = beg + u;
                q[u] = einfo[p < last ? p : last];
            }
#pragma unroll
            for (int u = 0; u < 8; ++u) {
                const int s = q[u].x & 0xFFFFF;
                v[u] = *(const short8*)(feat + (size_t)s * DIM + l16 * 8);
            }
            float acc[8] = {0.f, 0.f, 0.f, 0.f, 0.f, 0.f, 0.f, 0.f};
            int cur = ((unsigned)q[0].x) >> 20;

            for (int e = beg; e < end; e += 8) {
                // prefetch next einfo chunk (broadcast loads, L1-resident)
#pragma unroll
                for (int u = 0; u < 8; ++u) {
                    int p = e + 8 + u;
                    qn[u] = einfo[p < last ? p : last];
                }
                // compute current chunk
#pragma unroll
                for (int u = 0; u < 8; ++u) {
                    if (e + u < end) {
                        const int s = ((unsigned)q[u].x) >> 20;
                        if (s != cur) {
                            short8 o;
#pragma unroll
                            for (int j = 0; j < 8; ++j) o[j] = (short)f2h(acc[j]);
                            *(short8*)(Arow + cur * DIM + l16 * 8) = o;
#pragma unroll
                            for (int j = 0; j < 8; ++j) acc[j] = 0.f;
                            cur = s;
                        }
                        const float sc = __int_as_float(q[u].y);
                        const short8 ve = v[u];
#pragma unroll
                        for (int j = 0; j < 8; ++j)
                            acc[j] += h2f((unsigned short)ve[j]) * sc;
                    }
                }
                // issue next chunk's feature gathers (addresses already known)
#pragma unroll
                for (int u = 0; u < 8; ++u) {
                    const int s = qn[u].x & 0xFFFFF;
                    v[u] = *(const short8*)(feat + (size_t)s * DIM + l16 * 8);
                    q[u] = qn[u];
                }
            }
            // final flush
            short8 o;
#pragma unroll
            for (int j = 0; j < 8; ++j) o[j] = (short)f2h(acc[j]);
            *(short8*)(Arow + cur * DIM + l16 * 8) = o;
        }
    }
    __syncthreads();

    // ---- phase 2: MFMA ----
    const int lane = tid & 63;
    const int w = tid >> 6;                 // wave id -> h-tiles 2w, 2w+1
    const int m = lane & 15, kq = lane >> 4;
    const unsigned short* arow = &A16[m * A16ROW + kq * 8];
    f32x4 acc0 = {0.f, 0.f, 0.f, 0.f};
    f32x4 acc1 = {0.f, 0.f, 0.f, 0.f};

#pragma unroll 4
    for (int kt = 0; kt < NKT; ++kt) {
        short8 a = *(const short8*)(arow + kt * 32);
        short8 b0 = *(const short8*)(Wp + ((size_t)(kt * 8 + 2 * w) * 64 + lane) * 8);
        short8 b1 = *(const short8*)(Wp + ((size_t)(kt * 8 + 2 * w + 1) * 64 + lane) * 8);
        acc0 = __builtin_amdgcn_mfma_f32_16x16x32_f16(
            __builtin_bit_cast(half8, a), __builtin_bit_cast(half8, b0), acc0, 0, 0, 0);
        acc1 = __builtin_amdgcn_mfma_f32_16x16x32_f16(
            __builtin_bit_cast(half8, a), __builtin_bit_cast(half8, b1), acc1, 0, 0, 0);
    }

    // ---- epilogue: bias + relu + f16 store (C/D: col=lane&15, row=quad*4+r) ----
    const int col = lane & 15;
    const int rbase = (lane >> 4) * 4;
    const int h0 = 32 * w + col;
    const int h1 = h0 + 16;
    const float bv0 = bias[h0], bv1 = bias[h1];
#pragma unroll
    for (int r = 0; r < 4; ++r) {
        const size_t nrow = ((size_t)blk * 16 + rbase + r) * DIM;
        out[nrow + h0] = f2h(fmaxf(acc0[r] + bv0, 0.f));
        out[nrow + h1] = f2h(fmaxf(acc1[r] + bv1, 0.f));
    }
}

// ------------------------------------------------------------------ head ----
__global__ __launch_bounds__(256) void final_kernel(const unsigned short* __restrict__ h2,
                                                    const float* __restrict__ w,
                                                    const float* __restrict__ b,
                                                    float* __restrict__ out) {
    int gid = blockIdx.x * 256 + threadIdx.x;
    int node = gid >> 6;
    int lane = gid & 63;
    if (node >= NNODES) return;
    const unsigned short* row = h2 + (size_t)node * DIM;
    float v = h2f(row[lane]) * w[lane] + h2f(row[lane + 64]) * w[lane + 64];
#pragma unroll
    for (int off = 32; off; off >>= 1) v += __shfl_xor(v, off);
    if (lane == 0) out[node] = 1.0f / (1.0f + __expf(-(v + b[0])));
}

// ---------------------------------------------------------------- launch ----
extern "C" void kernel_launch(void* const* d_in, const int* in_sizes, int n_in,
                              void* d_out, int out_size, void* d_ws, size_t ws_size,
                              hipStream_t stream) {
    const float* x      = (const float*)d_in[0];
    const int*   ei     = (const int*)d_in[1];
    const int*   et     = (const int*)d_in[2];
    const float* Wrel1  = (const float*)d_in[3];
    const float* Wroot1 = (const float*)d_in[4];
    const float* b1     = (const float*)d_in[5];
    const float* Wrel2  = (const float*)d_in[6];
    const float* Wroot2 = (const float*)d_in[7];
    const float* b2     = (const float*)d_in[8];
    const float* outw   = (const float*)d_in[9];
    const float* outb   = (const float*)d_in[10];
    const int* src = ei;
    const int* dst = ei + NEDGES;

    // workspace layout (~100 MB, 16B-aligned chunks)
    char* ws = (char*)d_ws;
    int*            cnt    = (int*)(ws + 0);                     //  3,200,000
    int*            bsum   = (int*)(ws + 3200000);               //      4,096
    int*            segend = (int*)(ws + 3204096);               //  3,200,000
    int2*           einfo  = (int2*)(ws + 6404096);              // 12,800,000 (+slack)
    unsigned short* xh     = (unsigned short*)(ws + 19204352);   // 25,600,000
    unsigned short* h1     = (unsigned short*)(ws + 44804352);   // 25,600,000
    unsigned short* h2     = (unsigned short*)(ws + 70404352);   // 25,600,000
    unsigned short* Wp1    = (unsigned short*)(ws + 96004352);   //    294,912
    unsigned short* Wp2    = (unsigned short*)(ws + 96299264);   //    294,912
    float*          inv    = (float*)(ws + 96594176);            //  3,200,000
    // end: 99,794,176 B

    hipMemsetAsync(cnt, 0, (size_t)NSEG * 4, stream);
    // grid sized for the LARGER of the two fused jobs (cvt: 3.2M > edges: 1.6M)
    count_cvt<<<(CVT4 + 255) / 256, 256, 0, stream>>>(dst, et, cnt, x, xh);
    scan_pass1<<<NSCAN, 256, 0, stream>>>(cnt, bsum, inv);
    scan_pass2<<<1, 64, 0, stream>>>(bsum);
    scan_pass3<<<NSCAN, 256, 0, stream>>>(cnt, bsum, segend);
    bucket_kernel<<<(NEDGES + 255) / 256, 256, 0, stream>>>(src, dst, et, inv, segend, einfo);
    pack_w2<<<NKT * 8 * 2, 64, 0, stream>>>(Wrel1, Wroot1, Wrel2, Wroot2, Wp1, Wp2);

    fused_layer<<<NNODES / 16, 256, 0, stream>>>(xh, segend, einfo, Wp1, b1, h1);
    fused_layer<<<NNODES / 16, 256, 0, stream>>>(h1, segend, einfo, Wp2, b2, h2);

    final_kernel<<<(NNODES * 64 + 255) / 256, 256, 0, stream>>>(h2, outw, outb, (float*)d_out);
}